// Round 10
// baseline (2048.690 us; speedup 1.0000x reference)
//
#include <hip/hip_runtime.h>
#include <cstdint>
#include <cstddef>

#define DEPTH 6
#define NB    16
#define NSEQ  512
#define EMB   1024
#define NHEAD 16
#define HDIM  64
#define FFD   2048
#define NTOK  (NB * NSEQ)   // 8192

typedef unsigned short u16;
using bf16x8 = __attribute__((ext_vector_type(8))) __bf16;
using f32x4  = __attribute__((ext_vector_type(4))) float;
using f32x16 = __attribute__((ext_vector_type(16))) float;
using u16x4  = __attribute__((ext_vector_type(4))) u16;
using u16x8  = __attribute__((ext_vector_type(8))) u16;

typedef __attribute__((address_space(1))) uint32_t* as1_u32p;
typedef __attribute__((address_space(3))) uint32_t* as3_u32p;

__device__ __forceinline__ u16 f2bf(float f) {
  union { float f; uint32_t u; } v; v.f = f;
  uint32_t u = v.u;
  return (u16)((u + 0x7FFFu + ((u >> 16) & 1u)) >> 16);
}

__device__ __forceinline__ void gload_lds16(const u16* g, u16* l) {
  void* gp = const_cast<u16*>(g);
  __builtin_amdgcn_global_load_lds((as1_u32p)gp, (as3_u32p)l, 16, 0, 0);
}

// Stage a 16KB tile, linear LDS dest, XOR-swizzled global source (rule #21).
// 256-thread version (4 VMEM instr/thread).
template<int ROWBYTES>
__device__ __forceinline__ void stage16k(const u16* g0, int ldk, u16* lds) {
  int t = threadIdx.x;
#pragma unroll
  for (int i = 0; i < 4; ++i) {
    int off = (i * 256 + t) * 16;          // LDS byte offset
    int row = off / ROWBYTES;
    int pc  = (off % ROWBYTES) >> 4;
    int lc  = pc ^ (row & 7);
    gload_lds16(g0 + (size_t)row * ldk + lc * 8, lds + (off >> 1));
  }
}

// 128-thread version (8 VMEM instr/thread).
template<int ROWBYTES>
__device__ __forceinline__ void stage16k_t128(const u16* g0, int ldk, u16* lds) {
  int t = threadIdx.x;
#pragma unroll
  for (int i = 0; i < 8; ++i) {
    int off = (i * 128 + t) * 16;
    int row = off / ROWBYTES;
    int pc  = (off % ROWBYTES) >> 4;
    int lc  = pc ^ (row & 7);
    gload_lds16(g0 + (size_t)row * ldk + lc * 8, lds + (off >> 1));
  }
}

// ------------- weight prep (ALL weights, one dispatch) ---------------------
__global__ __launch_bounds__(256)
void wprep_all(const float* __restrict__ Wq, const float* __restrict__ Wk,
               const float* __restrict__ Wv, const float* __restrict__ Wp,
               const float* __restrict__ W1, const float* __restrict__ W2,
               u16* __restrict__ wqkv, u16* __restrict__ wp,
               u16* __restrict__ w1t, u16* __restrict__ w2t)
{
  int bid = blockIdx.x;
  const float* W; u16* out; int K, N; size_t inL, outL, outOff; int r;
  if (bid < 4608) {              // Wq/Wk/Wv -> wqkv, section offset
    int which = bid / 1536; r = bid % 1536;
    W = (which == 0) ? Wq : (which == 1) ? Wk : Wv;
    out = wqkv; K = 1024; N = 1024;
    inL = 1048576; outL = 3145728; outOff = (size_t)which * 1048576;
  } else if (bid < 6144) {
    W = Wp; out = wp; r = bid - 4608; K = 1024; N = 1024;
    inL = 1048576; outL = 1048576; outOff = 0;
  } else if (bid < 9216) {
    W = W1; out = w1t; r = bid - 6144; K = 1024; N = 2048;
    inL = 2097152; outL = 2097152; outOff = 0;
  } else {
    W = W2; out = w2t; r = bid - 9216; K = 2048; N = 1024;
    inL = 2097152; outL = 2097152; outOff = 0;
  }
  int ntiles = N >> 6, ktiles = K >> 6;
  int l = r / (ktiles * ntiles);
  int rr = r % (ktiles * ntiles);
  int kt = rr / ntiles, nt = rr % ntiles;
  const float* in = W + (size_t)l * inL + (size_t)(kt * 64) * N + nt * 64;
  u16* o = out + (size_t)l * outL + outOff + (size_t)(nt * 64) * K + kt * 64;
  __shared__ float tile[64][65];
  int t = threadIdx.x;
  int tr = t >> 4, tc = (t & 15) * 4;
#pragma unroll
  for (int i = 0; i < 4; ++i) {
    f32x4 v = *(const f32x4*)(in + (size_t)(tr + i * 16) * N + tc);
    tile[tr + i * 16][tc + 0] = v[0];
    tile[tr + i * 16][tc + 1] = v[1];
    tile[tr + i * 16][tc + 2] = v[2];
    tile[tr + i * 16][tc + 3] = v[3];
  }
  __syncthreads();
#pragma unroll
  for (int i = 0; i < 4; ++i) {
    int nr = tr + i * 16;
    u16x4 ov;
    ov[0] = f2bf(tile[tc + 0][nr]);
    ov[1] = f2bf(tile[tc + 1][nr]);
    ov[2] = f2bf(tile[tc + 2][nr]);
    ov[3] = f2bf(tile[tc + 3][nr]);
    *(u16x4*)(o + (size_t)nr * K + tc) = ov;
  }
}

// ---------------- embed: concat cls + pos add ------------------------------
__global__ __launch_bounds__(256)
void embed_k(const float* __restrict__ x, const float* __restrict__ cls,
             const float* __restrict__ pos, float* __restrict__ H)
{
  int row = blockIdx.x, t = threadIdx.x;
  int b_ = row >> 9, n = row & 511;
  int c = t * 4;
  f32x4 p = *(const f32x4*)(pos + (size_t)n * EMB + c);
  f32x4 s;
  if (n == 0) s = *(const f32x4*)(cls + c);
  else        s = *(const f32x4*)(x + ((size_t)b_ * 511 + (n - 1)) * EMB + c);
  f32x4 o = s + p;
  *(f32x4*)(H + (size_t)row * EMB + c) = o;
}

// ---------------- layernorm: wave-per-row, no LDS, no barriers -------------
__global__ __launch_bounds__(256)
void ln_k(const float* __restrict__ H, const float* __restrict__ g,
          const float* __restrict__ b, u16* __restrict__ out)
{
  int lane = threadIdx.x & 63, w = threadIdx.x >> 6;
  int row = blockIdx.x * 4 + w;
  const float* hp = H + (size_t)row * EMB;
  f32x4 v[4];
  float s = 0.f, ss = 0.f;
#pragma unroll
  for (int i = 0; i < 4; ++i) {
    v[i] = *(const f32x4*)(hp + lane * 4 + i * 256);
#pragma unroll
    for (int j = 0; j < 4; ++j) { s += v[i][j]; ss += v[i][j] * v[i][j]; }
  }
#pragma unroll
  for (int m = 1; m <= 32; m <<= 1) { s += __shfl_xor(s, m); ss += __shfl_xor(ss, m); }
  float mean = s * (1.0f / EMB);
  float var  = ss * (1.0f / EMB) - mean * mean;
  float rs = rsqrtf(var + 1e-5f);
#pragma unroll
  for (int i = 0; i < 4; ++i) {
    f32x4 gg = *(const f32x4*)(g + lane * 4 + i * 256);
    f32x4 bb = *(const f32x4*)(b + lane * 4 + i * 256);
    u16x4 o;
#pragma unroll
    for (int j = 0; j < 4; ++j) o[j] = f2bf((v[i][j] - mean) * rs * gg[j] + bb[j]);
    *(u16x4*)(out + (size_t)row * EMB + lane * 4 + i * 256) = o;
  }
}

// ====== 128x128 GEMM, 2 waves x (64x128 wave tile), single-buffer =========
// LDS-read reuse: per ks a wave reads 4 A-frags + 8 B-frags for 32 MFMA
// (23 reads/MFLOP vs 30.5 for the 2x2/64x64 decomposition).
// EPI: 0=QKV scatter via LDS-coalesced epi  1=+resid->H(f32)
//      2=+bias,gelu->outB via LDS epi       3=+bias+resid->H(f32)
template<int EPI>
__global__ __launch_bounds__(128)
void gemm_k(const u16* __restrict__ A, const u16* __restrict__ Bt,
            int nbn, int K,
            const float* __restrict__ bias, float* __restrict__ H,
            u16* __restrict__ outB,
            u16* __restrict__ qo, u16* __restrict__ ko, u16* __restrict__ vto)
{
  __shared__ u16 sm[16384];            // 32 KB: A tile | B tile; reused by epi
  int cpx = gridDim.x >> 3;
  int logical = (blockIdx.x & 7) * cpx + (blockIdx.x >> 3);
  int bm = logical / nbn, bn = logical % nbn;
  int t = threadIdx.x, lane = t & 63, w = t >> 6;   // w in {0,1}
  const u16* Ab = A  + (size_t)(bm * 128) * K;
  const u16* Bb = Bt + (size_t)(bn * 128) * K;
  int nkt = K >> 6;

  const f32x4 vzero = {0.f, 0.f, 0.f, 0.f};
  f32x4 acc[4][8];
#pragma unroll
  for (int i = 0; i < 4; ++i)
#pragma unroll
    for (int j = 0; j < 8; ++j) acc[i][j] = vzero;

  int r0 = lane & 15;
  int hi = lane >> 4;
  int kk0 = hi * 8;

  for (int kt = 0; kt < nkt; ++kt) {
    stage16k_t128<128>(Ab + kt * 64, K, sm);
    stage16k_t128<128>(Bb + kt * 64, K, sm + 8192);
    __syncthreads();                    // drains vmcnt: tile ready
    const char* smAp = (const char*)sm;
    const char* smBp = (const char*)(sm + 8192);
#pragma unroll
    for (int ks = 0; ks < 2; ++ks) {
      int kk = ks * 32 + kk0;
      bf16x8 a[4], b[8];
#pragma unroll
      for (int mf = 0; mf < 4; ++mf) {
        int row = w * 64 + mf * 16 + r0;
        a[mf] = *(const bf16x8*)(smAp + row * 128 + ((kk * 2) ^ ((row & 7) << 4)));
      }
#pragma unroll
      for (int nf = 0; nf < 8; ++nf) {
        int row = nf * 16 + r0;
        b[nf] = *(const bf16x8*)(smBp + row * 128 + ((kk * 2) ^ ((row & 7) << 4)));
      }
#pragma unroll
      for (int mf = 0; mf < 4; ++mf)
#pragma unroll
        for (int nf = 0; nf < 8; ++nf)
          acc[mf][nf] = __builtin_amdgcn_mfma_f32_16x16x32_bf16(a[mf], b[nf], acc[mf][nf], 0, 0, 0);
    }
    __syncthreads();                    // readers done; next stage may overwrite
  }

  if (EPI == 1 || EPI == 3) {
    int m0 = bm * 128 + w * 64;
    int n0 = bn * 128;
#pragma unroll
    for (int mf = 0; mf < 4; ++mf) {
#pragma unroll
      for (int nf = 0; nf < 8; ++nf) {
        int col  = n0 + nf * 16 + r0;
        int rowb = m0 + mf * 16 + hi * 4;
#pragma unroll
        for (int j = 0; j < 4; ++j) {
          float v = acc[mf][nf][j];
          size_t idx = (size_t)(rowb + j) * EMB + col;
          if (EPI == 1) H[idx] = v + H[idx];
          else          H[idx] = v + bias[col] + H[idx];
        }
      }
    }
    return;
  }

  // ---- LDS-coalesced epilogue (EPI 0 / 2) --------------------------------
  int sec = (bn * 128) >> 10;           // EPI0: 0=q 1=k 2=v ; EPI2: always 0/1
  bool vsec = (EPI == 0) && (sec == 2);
#pragma unroll
  for (int mf = 0; mf < 4; ++mf) {
#pragma unroll
    for (int nf = 0; nf < 8; ++nf) {
      int colL = nf * 16 + r0;
#pragma unroll
      for (int j = 0; j < 4; ++j) {
        int rowL = w * 64 + mf * 16 + hi * 4 + j;
        float v = acc[mf][nf][j];
        if (EPI == 2) {
          float xg = v + bias[bn * 128 + colL];
          v = 0.5f * xg * (1.0f + erff(xg * 0.70710678118654752f));
        }
        u16 o = f2bf(v);
        if (!vsec)
          sm[rowL * 128 + (colL & 7) + ((((colL >> 3) ^ (rowL & 7))) << 3)] = o;
        else  // v: store transposed [c][n]
          sm[colL * 128 + (rowL & 7) + ((((rowL >> 3) ^ (colL & 7))) << 3)] = o;
      }
    }
  }
  __syncthreads();

  int c  = t & 15;                      // chunk of 8 cols
  int rb = t >> 4;                      // 0..7
  if (!vsec) {
#pragma unroll
    for (int i = 0; i < 16; ++i) {
      int row = rb * 16 + i;
      u16x8 v = *(const u16x8*)(sm + row * 128 + ((c ^ (row & 7)) << 3));
      if (EPI == 2) {
        int rowg = bm * 128 + row;
        int colg = bn * 128 + c * 8;
        *(u16x8*)(outB + (size_t)rowg * FFD + colg) = v;
      } else {
        int n_ = bm * 128 + row;
        int b_ = n_ >> 9, tok = n_ & 511;
        int c0 = (bn * 128 - sec * 1024) + c * 8;
        int hh = c0 >> 6, d0 = c0 & 63;
        u16* dst = (sec == 0) ? qo : ko;
        *(u16x8*)(dst + (((size_t)(b_ * NHEAD + hh) * NSEQ + tok) * HDIM) + d0) = v;
      }
    }
  } else {
#pragma unroll
    for (int i = 0; i < 16; ++i) {
      int rowp = rb * 16 + i;           // local c (head*64+d)
      u16x8 v = *(const u16x8*)(sm + rowp * 128 + ((c ^ (rowp & 7)) << 3));
      int c0 = (bn * 128 - 2048) + rowp;
      int hh = c0 >> 6, d = c0 & 63;
      int tok0 = bm * 128 + c * 8;
      int b_ = tok0 >> 9;
      *(u16x8*)(vto + ((size_t)(b_ * NHEAD + hh) * HDIM + d) * NSEQ + (tok0 & 511)) = v;
    }
  }
}

// ============== fused attention: swapped-QK^T 32x32, online softmax ========
// Counted vmcnt(8) + raw s_barrier (T4) + setprio around MFMA clusters (T5).
__global__ __launch_bounds__(256, 2)
void attn_k(const u16* __restrict__ Q, const u16* __restrict__ Kk,
            const u16* __restrict__ Vt, u16* __restrict__ AO)
{
  __shared__ u16 bufK[2][8192];    // 16KB chunk: K[128 keys][64 d]
  __shared__ u16 bufV[2][8192];    // 16KB chunk: V^T[64 d][128 keys]
  int bid = blockIdx.x;
  int logical = (bid & 7) * 128 + (bid >> 3);   // XCD swizzle (1024 blocks)
  int bh = logical >> 2, qt = logical & 3;
  int t = threadIdx.x, lane = t & 63, w = t >> 6;
  int l31 = lane & 31, hi32 = lane >> 5;
  const u16* Kb = Kk + (size_t)bh * (NSEQ * HDIM);
  const u16* Vb = Vt + (size_t)bh * (HDIM * NSEQ);

  // Q B-fragments: lane l31 -> q-row, k = 16*tk + 8*hi32 + e
  int qbase = qt * 128 + w * 32;
  const u16* Qp = Q + ((size_t)bh * NSEQ + qbase + l31) * HDIM;
  bf16x8 qf[4];
#pragma unroll
  for (int tk = 0; tk < 4; ++tk)
    qf[tk] = *(const bf16x8*)(Qp + 16 * tk + 8 * hi32);

  // prologue: stage chunks 0 and 1 (8 VMEM instr/thread each)
  stage16k<128>(Kb, HDIM, &bufK[0][0]);
  stage16k<256>(Vb, NSEQ, &bufV[0][0]);
  stage16k<128>(Kb + 128 * HDIM, HDIM, &bufK[1][0]);
  stage16k<256>(Vb + 128, NSEQ, &bufV[1][0]);

  f32x16 accO[2];
#pragma unroll
  for (int r = 0; r < 16; ++r) { accO[0][r] = 0.f; accO[1][r] = 0.f; }
  float m_run = -1e30f, den = 0.f;
  const float inv32 = 0.03125f;      // 1/sqrt(EMB)

  for (int c = 0; c < 4; ++c) {
    if (c == 3) asm volatile("s_waitcnt vmcnt(0)" ::: "memory");
    else        asm volatile("s_waitcnt vmcnt(8)" ::: "memory");   // own chunk landed
    asm volatile("s_barrier" ::: "memory");
    // ---- S chunk: 4 key-tiles x 4 k-steps of mfma32(K, Q) ----
    const char* smK = (const char*)&bufK[c & 1][0];
    f32x16 s[4];
    __builtin_amdgcn_s_setprio(1);
#pragma unroll
    for (int kt = 0; kt < 4; ++kt) {
#pragma unroll
      for (int r = 0; r < 16; ++r) s[kt][r] = 0.f;
#pragma unroll
      for (int tk = 0; tk < 4; ++tk) {
        int row = kt * 32 + l31;
        bf16x8 kf = *(const bf16x8*)(smK + row * 128 +
                      ((32 * tk + 16 * hi32) ^ ((row & 7) << 4)));
        s[kt] = __builtin_amdgcn_mfma_f32_32x32x16_bf16(kf, qf[tk], s[kt], 0, 0, 0);
      }
    }
    __builtin_amdgcn_s_setprio(0);
    // ---- online softmax (row = in-lane + xor32 partner) ----
    float mc = -1e30f;
#pragma unroll
    for (int kt = 0; kt < 4; ++kt)
#pragma unroll
      for (int r = 0; r < 16; ++r) mc = fmaxf(mc, s[kt][r]);
    mc = fmaxf(mc, __shfl_xor(mc, 32));
    float newm = fmaxf(m_run, mc);
    float fac = __expf((m_run - newm) * inv32);
    den *= fac;
#pragma unroll
    for (int r = 0; r < 16; ++r) { accO[0][r] *= fac; accO[1][r] *= fac; }
    m_run = newm;
#pragma unroll
    for (int kt = 0; kt < 4; ++kt)
#pragma unroll
      for (int r = 0; r < 16; ++r) {
        float p = __expf((s[kt][r] - newm) * inv32);
        den += p;
        s[kt][r] = p;
      }
    // pack P to bf16 pairs: pb[j] = {p[2j] lo, p[2j+1] hi}
    uint32_t pb[32];
#pragma unroll
    for (int j = 0; j < 32; ++j) {
      float lo = s[j >> 3][(2 * j) & 15];
      float hi = s[j >> 3][((2 * j) & 15) + 1];
      asm("v_cvt_pk_bf16_f32 %0, %1, %2" : "=v"(pb[j]) : "v"(lo), "v"(hi));
    }
    // ---- PV: per k-step build A-frag via 2 permlane32_swap ----
    const char* smV = (const char*)&bufV[c & 1][0];
#pragma unroll
    for (int ks = 0; ks < 8; ++ks) {
      uint32_t x0 = pb[4 * ks], y0 = pb[4 * ks + 2];
      uint32_t x1 = pb[4 * ks + 1], y1 = pb[4 * ks + 3];
      asm("v_permlane32_swap_b32 %0, %1" : "+v"(x0), "+v"(y0));
      asm("v_permlane32_swap_b32 %0, %1" : "+v"(x1), "+v"(y1));
      union { uint4 u; bf16x8 v; } pa;
      pa.u = make_uint4(x0, x1, y0, y1);
      __builtin_amdgcn_s_setprio(1);
#pragma unroll
      for (int dt = 0; dt < 2; ++dt) {
        int row = dt * 32 + l31;
        bf16x8 vb = *(const bf16x8*)(smV + row * 256 +
                      ((32 * ks + 16 * hi32) ^ ((row & 7) << 4)));
        accO[dt] = __builtin_amdgcn_mfma_f32_32x32x16_bf16(pa.v, vb, accO[dt], 0, 0, 0);
      }
      __builtin_amdgcn_s_setprio(0);
    }
    asm volatile("s_barrier" ::: "memory");   // all waves released buf[c&1]
    if (c + 2 < 4) {
      stage16k<128>(Kb + (size_t)(c + 2) * 128 * HDIM, HDIM, &bufK[c & 1][0]);
      stage16k<256>(Vb + (c + 2) * 128, NSEQ, &bufV[c & 1][0]);
    }
  }

  // ---- epilogue: O[q][d], q=(r&3)+8*(r>>2)+4*hi32, d=l31+32*dt ----
  float denf = den + __shfl_xor(den, 32);
  float rden = 1.0f / denf;
  int b_ = bh >> 4, hh = bh & 15;
#pragma unroll
  for (int r = 0; r < 16; ++r) {
    int qoff = (r & 3) + 8 * (r >> 2) + 4 * hi32;
    float rd = __shfl(rden, qoff);
    int tok = qbase + qoff;
    size_t base = ((size_t)(b_ * NSEQ + tok)) * EMB + hh * 64 + l31;
    AO[base]      = f2bf(accO[0][r] * rd);
    AO[base + 32] = f2bf(accO[1][r] * rd);
  }
}

// ---------------- launch ---------------------------------------------------
extern "C" void kernel_launch(void* const* d_in, const int* in_sizes, int n_in,
                              void* d_out, int out_size, void* d_ws, size_t ws_size,
                              hipStream_t stream)
{
  const float* x    = (const float*)d_in[0];
  const float* cls  = (const float*)d_in[1];
  const float* pos  = (const float*)d_in[2];
  const float* Wq   = (const float*)d_in[3];
  const float* Wk   = (const float*)d_in[4];
  const float* Wv   = (const float*)d_in[5];
  const float* Wp   = (const float*)d_in[6];
  const float* ln1g = (const float*)d_in[7];
  const float* ln1b = (const float*)d_in[8];
  const float* ln2g = (const float*)d_in[9];
  const float* ln2b = (const float*)d_in[10];
  const float* W1   = (const float*)d_in[11];
  const float* b1   = (const float*)d_in[12];
  const float* W2   = (const float*)d_in[13];
  const float* b2   = (const float*)d_in[14];
  float* H = (float*)d_out;          // residual stream lives in d_out (fp32)

  char* ws = (char*)d_ws;            // 160 MiB used
  u16* wqkv = (u16*)(ws + 0);                // [6][3072][1024] bf16 (B^T)
  u16* wp   = (u16*)(ws + 37748736);         // [6][1024][1024]
  u16* w1t  = (u16*)(ws + 50331648);         // [6][2048][1024]
  u16* w2t  = (u16*)(ws + 75497472);         // [6][1024][2048]
  u16* xn   = (u16*)(ws + 100663296);        // [8192][1024] (also attn out)
  u16* qb   = (u16*)(ws + 117440512);        // [256][512][64]
  u16* kb   = (u16*)(ws + 134217728);        // [256][512][64]
  u16* vtb  = (u16*)(ws + 150994944);        // [256][64][512]
  u16* ffb  = qb;                            // [8192][2048] aliases q+k

  wprep_all<<<12288, 256, 0, stream>>>(Wq, Wk, Wv, Wp, W1, W2,
                                       wqkv, wp, w1t, w2t);
  embed_k<<<NTOK, 256, 0, stream>>>(x, cls, pos, H);

  for (int l = 0; l < DEPTH; ++l) {
    ln_k<<<2048, 256, 0, stream>>>(H, ln1g + l * EMB, ln1b + l * EMB, xn);
    gemm_k<0><<<64 * 24, 128, 0, stream>>>(xn, wqkv + (size_t)l * 3145728, 24, 1024,
                                           nullptr, nullptr, nullptr, qb, kb, vtb);
    attn_k<<<1024, 256, 0, stream>>>(qb, kb, vtb, xn);
    gemm_k<1><<<64 * 8, 128, 0, stream>>>(xn, wp + (size_t)l * 1048576, 8, 1024,
                                          nullptr, H, nullptr, nullptr, nullptr, nullptr);
    ln_k<<<2048, 256, 0, stream>>>(H, ln2g + l * EMB, ln2b + l * EMB, xn);
    gemm_k<2><<<64 * 16, 128, 0, stream>>>(xn, w1t + (size_t)l * 2097152, 16, 1024,
                                           b1 + l * FFD, nullptr, ffb, nullptr, nullptr, nullptr);
    gemm_k<3><<<64 * 8, 128, 0, stream>>>(ffb, w2t + (size_t)l * 2097152, 8, 2048,
                                          b2 + l * EMB, H, nullptr, nullptr, nullptr, nullptr);
  }
}

// Round 11
// 1402.041 us; speedup vs baseline: 1.4612x; 1.4612x over previous
//
#include <hip/hip_runtime.h>
#include <cstdint>
#include <cstddef>

#define DEPTH 6
#define NB    16
#define NSEQ  512
#define EMB   1024
#define NHEAD 16
#define HDIM  64
#define FFD   2048
#define NTOK  (NB * NSEQ)   // 8192

typedef unsigned short u16;
using bf16x8 = __attribute__((ext_vector_type(8))) __bf16;
using f32x4  = __attribute__((ext_vector_type(4))) float;
using f32x16 = __attribute__((ext_vector_type(16))) float;
using u16x4  = __attribute__((ext_vector_type(4))) u16;
using u16x8  = __attribute__((ext_vector_type(8))) u16;

typedef __attribute__((address_space(1))) uint32_t* as1_u32p;
typedef __attribute__((address_space(3))) uint32_t* as3_u32p;

__device__ __forceinline__ u16 f2bf(float f) {
  union { float f; uint32_t u; } v; v.f = f;
  uint32_t u = v.u;
  return (u16)((u + 0x7FFFu + ((u >> 16) & 1u)) >> 16);
}

__device__ __forceinline__ void gload_lds16(const u16* g, u16* l) {
  void* gp = const_cast<u16*>(g);
  __builtin_amdgcn_global_load_lds((as1_u32p)gp, (as3_u32p)l, 16, 0, 0);
}

// Stage a 16KB tile, linear LDS dest, XOR-swizzled global source (rule #21).
// 256-thread version (4 VMEM instr/thread).
template<int ROWBYTES>
__device__ __forceinline__ void stage16k(const u16* g0, int ldk, u16* lds) {
  int t = threadIdx.x;
#pragma unroll
  for (int i = 0; i < 4; ++i) {
    int off = (i * 256 + t) * 16;          // LDS byte offset
    int row = off / ROWBYTES;
    int pc  = (off % ROWBYTES) >> 4;
    int lc  = pc ^ (row & 7);
    gload_lds16(g0 + (size_t)row * ldk + lc * 8, lds + (off >> 1));
  }
}

// ------------- weight prep: TWO K-adjacent 64x64 tiles per block -----------
// fp32 [K][N] -> bf16 [N][K] (B^T layout). 2x MLP: both tiles' loads issue
// before the single barrier; tile-B reads overlap tile-A stores after it.
__global__ __launch_bounds__(256)
void wprep_all(const float* __restrict__ Wq, const float* __restrict__ Wk,
               const float* __restrict__ Wv, const float* __restrict__ Wp,
               const float* __restrict__ W1, const float* __restrict__ W2,
               u16* __restrict__ wqkv, u16* __restrict__ wp,
               u16* __restrict__ w1t, u16* __restrict__ w2t)
{
  int bid = blockIdx.x;
  const float* W; u16* out; int K, N; size_t inL, outL, outOff; int r2;
  if (bid < 2304) {              // Wq/Wk/Wv -> wqkv, section offset
    int which = bid / 768; r2 = bid % 768;
    W = (which == 0) ? Wq : (which == 1) ? Wk : Wv;
    out = wqkv; K = 1024; N = 1024;
    inL = 1048576; outL = 3145728; outOff = (size_t)which * 1048576;
  } else if (bid < 3072) {
    W = Wp; out = wp; r2 = bid - 2304; K = 1024; N = 1024;
    inL = 1048576; outL = 1048576; outOff = 0;
  } else if (bid < 4608) {
    W = W1; out = w1t; r2 = bid - 3072; K = 1024; N = 2048;
    inL = 2097152; outL = 2097152; outOff = 0;
  } else {
    W = W2; out = w2t; r2 = bid - 4608; K = 2048; N = 1024;
    inL = 2097152; outL = 2097152; outOff = 0;
  }
  int ntiles = N >> 6, k2tiles = K >> 7;   // pairs along K
  int l = r2 / (k2tiles * ntiles);
  int rr = r2 % (k2tiles * ntiles);
  int kt = (rr / ntiles) * 2, nt = rr % ntiles;
  const float* in0 = W + (size_t)l * inL + (size_t)(kt * 64) * N + nt * 64;
  u16* o0 = out + (size_t)l * outL + outOff + (size_t)(nt * 64) * K + kt * 64;

  __shared__ float tile[2][64][65];
  int t = threadIdx.x;
  int tr = t >> 4, tc = (t & 15) * 4;
  f32x4 v[2][4];
#pragma unroll
  for (int p = 0; p < 2; ++p) {
    const float* in = in0 + (size_t)p * 64 * N;
#pragma unroll
    for (int i = 0; i < 4; ++i)
      v[p][i] = *(const f32x4*)(in + (size_t)(tr + i * 16) * N + tc);
  }
#pragma unroll
  for (int p = 0; p < 2; ++p)
#pragma unroll
    for (int i = 0; i < 4; ++i) {
      tile[p][tr + i * 16][tc + 0] = v[p][i][0];
      tile[p][tr + i * 16][tc + 1] = v[p][i][1];
      tile[p][tr + i * 16][tc + 2] = v[p][i][2];
      tile[p][tr + i * 16][tc + 3] = v[p][i][3];
    }
  __syncthreads();
#pragma unroll
  for (int p = 0; p < 2; ++p) {
    u16* o = o0 + p * 64;
#pragma unroll
    for (int i = 0; i < 4; ++i) {
      int nr = tr + i * 16;
      u16x4 ov;
      ov[0] = f2bf(tile[p][tc + 0][nr]);
      ov[1] = f2bf(tile[p][tc + 1][nr]);
      ov[2] = f2bf(tile[p][tc + 2][nr]);
      ov[3] = f2bf(tile[p][tc + 3][nr]);
      *(u16x4*)(o + (size_t)nr * K + tc) = ov;
    }
  }
}

// ---------------- embed: concat cls + pos add ------------------------------
__global__ __launch_bounds__(256)
void embed_k(const float* __restrict__ x, const float* __restrict__ cls,
             const float* __restrict__ pos, float* __restrict__ H)
{
  int row = blockIdx.x, t = threadIdx.x;
  int b_ = row >> 9, n = row & 511;
  int c = t * 4;
  f32x4 p = *(const f32x4*)(pos + (size_t)n * EMB + c);
  f32x4 s;
  if (n == 0) s = *(const f32x4*)(cls + c);
  else        s = *(const f32x4*)(x + ((size_t)b_ * 511 + (n - 1)) * EMB + c);
  f32x4 o = s + p;
  *(f32x4*)(H + (size_t)row * EMB + c) = o;
}

// ---------------- layernorm: wave-per-row, no LDS, no barriers -------------
__global__ __launch_bounds__(256)
void ln_k(const float* __restrict__ H, const float* __restrict__ g,
          const float* __restrict__ b, u16* __restrict__ out)
{
  int lane = threadIdx.x & 63, w = threadIdx.x >> 6;
  int row = blockIdx.x * 4 + w;
  const float* hp = H + (size_t)row * EMB;
  f32x4 v[4];
  float s = 0.f, ss = 0.f;
#pragma unroll
  for (int i = 0; i < 4; ++i) {
    v[i] = *(const f32x4*)(hp + lane * 4 + i * 256);
#pragma unroll
    for (int j = 0; j < 4; ++j) { s += v[i][j]; ss += v[i][j] * v[i][j]; }
  }
#pragma unroll
  for (int m = 1; m <= 32; m <<= 1) { s += __shfl_xor(s, m); ss += __shfl_xor(ss, m); }
  float mean = s * (1.0f / EMB);
  float var  = ss * (1.0f / EMB) - mean * mean;
  float rs = rsqrtf(var + 1e-5f);
#pragma unroll
  for (int i = 0; i < 4; ++i) {
    f32x4 gg = *(const f32x4*)(g + lane * 4 + i * 256);
    f32x4 bb = *(const f32x4*)(b + lane * 4 + i * 256);
    u16x4 o;
#pragma unroll
    for (int j = 0; j < 4; ++j) o[j] = f2bf((v[i][j] - mean) * rs * gg[j] + bb[j]);
    *(u16x4*)(out + (size_t)row * EMB + lane * 4 + i * 256) = o;
  }
}

// ================= 128x128 GEMM, m97-exact single-buffer (32KB LDS) =======
// C[8192][N] = A[8192][K] * Bt[N][K]^T.  4 waves (2x2), BK=64, 3 blocks/CU.
// EPI: 0=QKV scatter via LDS-coalesced epi  1=+resid->H(f32)
//      2=+bias,gelu->outB via LDS epi       3=+bias+resid->H(f32)
template<int EPI>
__global__ __launch_bounds__(256, 3)
void gemm_k(const u16* __restrict__ A, const u16* __restrict__ Bt,
            int nbn, int K,
            const float* __restrict__ bias, float* __restrict__ H,
            u16* __restrict__ outB,
            u16* __restrict__ qo, u16* __restrict__ ko, u16* __restrict__ vto)
{
  __shared__ u16 sm[16384];            // 32 KB: A tile | B tile; reused by epi
  int cpx = gridDim.x >> 3;
  int logical = (blockIdx.x & 7) * cpx + (blockIdx.x >> 3);
  int bm = logical / nbn, bn = logical % nbn;
  int t = threadIdx.x, lane = t & 63, w = t >> 6;
  int wm = w >> 1, wn = w & 1;
  const u16* Ab = A  + (size_t)(bm * 128) * K;
  const u16* Bb = Bt + (size_t)(bn * 128) * K;
  int nkt = K >> 6;

  const f32x4 vzero = {0.f, 0.f, 0.f, 0.f};
  f32x4 acc[4][4];
#pragma unroll
  for (int i = 0; i < 4; ++i)
#pragma unroll
    for (int j = 0; j < 4; ++j) acc[i][j] = vzero;

  int r0 = lane & 15;
  int hi = lane >> 4;
  int kk0 = hi * 8;

  for (int kt = 0; kt < nkt; ++kt) {
    stage16k<128>(Ab + kt * 64, K, sm);
    stage16k<128>(Bb + kt * 64, K, sm + 8192);
    __syncthreads();                    // drains vmcnt: tile ready
    const char* smAp = (const char*)sm;
    const char* smBp = (const char*)(sm + 8192);
#pragma unroll
    for (int ks = 0; ks < 2; ++ks) {
      int kk = ks * 32 + kk0;
      bf16x8 a[4], b[4];
#pragma unroll
      for (int mf = 0; mf < 4; ++mf) {
        int row = wm * 64 + mf * 16 + r0;
        a[mf] = *(const bf16x8*)(smAp + row * 128 + ((kk * 2) ^ ((row & 7) << 4)));
      }
#pragma unroll
      for (int nf = 0; nf < 4; ++nf) {
        int row = wn * 64 + nf * 16 + r0;
        b[nf] = *(const bf16x8*)(smBp + row * 128 + ((kk * 2) ^ ((row & 7) << 4)));
      }
#pragma unroll
      for (int mf = 0; mf < 4; ++mf)
#pragma unroll
        for (int nf = 0; nf < 4; ++nf)
          acc[mf][nf] = __builtin_amdgcn_mfma_f32_16x16x32_bf16(a[mf], b[nf], acc[mf][nf], 0, 0, 0);
    }
    __syncthreads();                    // readers done; next stage may overwrite
  }

  if (EPI == 1 || EPI == 3) {
    int m0 = bm * 128 + wm * 64;
    int n0 = bn * 128 + wn * 64;
#pragma unroll
    for (int mf = 0; mf < 4; ++mf) {
#pragma unroll
      for (int nf = 0; nf < 4; ++nf) {
        int col  = n0 + nf * 16 + r0;
        int rowb = m0 + mf * 16 + hi * 4;
#pragma unroll
        for (int j = 0; j < 4; ++j) {
          float v = acc[mf][nf][j];
          size_t idx = (size_t)(rowb + j) * EMB + col;
          if (EPI == 1) H[idx] = v + H[idx];
          else          H[idx] = v + bias[col] + H[idx];
        }
      }
    }
    return;
  }

  // ---- LDS-coalesced epilogue (EPI 0 / 2) --------------------------------
  int sec = (bn * 128) >> 10;           // EPI0: 0=q 1=k 2=v ; EPI2: always 0/1
  bool vsec = (EPI == 0) && (sec == 2);
#pragma unroll
  for (int mf = 0; mf < 4; ++mf) {
#pragma unroll
    for (int nf = 0; nf < 4; ++nf) {
      int colL = wn * 64 + nf * 16 + r0;
#pragma unroll
      for (int j = 0; j < 4; ++j) {
        int rowL = wm * 64 + mf * 16 + hi * 4 + j;
        float v = acc[mf][nf][j];
        if (EPI == 2) {
          float xg = v + bias[bn * 128 + colL];
          v = 0.5f * xg * (1.0f + erff(xg * 0.70710678118654752f));
        }
        u16 o = f2bf(v);
        if (!vsec)
          sm[rowL * 128 + (colL & 7) + ((((colL >> 3) ^ (rowL & 7))) << 3)] = o;
        else  // v: store transposed [c][n]
          sm[colL * 128 + (rowL & 7) + ((((rowL >> 3) ^ (colL & 7))) << 3)] = o;
      }
    }
  }
  __syncthreads();

  int c  = t & 15;                      // chunk of 8 cols
  int rb = t >> 4;
  if (!vsec) {
#pragma unroll
    for (int i = 0; i < 8; ++i) {
      int row = rb * 8 + i;
      u16x8 v = *(const u16x8*)(sm + row * 128 + ((c ^ (row & 7)) << 3));
      if (EPI == 2) {
        int rowg = bm * 128 + row;
        int colg = bn * 128 + c * 8;
        *(u16x8*)(outB + (size_t)rowg * FFD + colg) = v;
      } else {
        int n_ = bm * 128 + row;
        int b_ = n_ >> 9, tok = n_ & 511;
        int c0 = (bn * 128 - sec * 1024) + c * 8;
        int hh = c0 >> 6, d0 = c0 & 63;
        u16* dst = (sec == 0) ? qo : ko;
        *(u16x8*)(dst + (((size_t)(b_ * NHEAD + hh) * NSEQ + tok) * HDIM) + d0) = v;
      }
    }
  } else {
#pragma unroll
    for (int i = 0; i < 8; ++i) {
      int rowp = rb * 8 + i;            // local c (head*64+d)
      u16x8 v = *(const u16x8*)(sm + rowp * 128 + ((c ^ (rowp & 7)) << 3));
      int c0 = (bn * 128 - 2048) + rowp;
      int hh = c0 >> 6, d = c0 & 63;
      int tok0 = bm * 128 + c * 8;
      int b_ = tok0 >> 9;
      *(u16x8*)(vto + ((size_t)(b_ * NHEAD + hh) * HDIM + d) * NSEQ + (tok0 & 511)) = v;
    }
  }
}

// ============== fused attention: swapped-QK^T 32x32, online softmax ========
// Counted vmcnt(8) + raw s_barrier (T4) + setprio around MFMA clusters (T5).
__global__ __launch_bounds__(256, 2)
void attn_k(const u16* __restrict__ Q, const u16* __restrict__ Kk,
            const u16* __restrict__ Vt, u16* __restrict__ AO)
{
  __shared__ u16 bufK[2][8192];    // 16KB chunk: K[128 keys][64 d]
  __shared__ u16 bufV[2][8192];    // 16KB chunk: V^T[64 d][128 keys]
  int bid = blockIdx.x;
  int logical = (bid & 7) * 128 + (bid >> 3);   // XCD swizzle (1024 blocks)
  int bh = logical >> 2, qt = logical & 3;
  int t = threadIdx.x, lane = t & 63, w = t >> 6;
  int l31 = lane & 31, hi32 = lane >> 5;
  const u16* Kb = Kk + (size_t)bh * (NSEQ * HDIM);
  const u16* Vb = Vt + (size_t)bh * (HDIM * NSEQ);

  // Q B-fragments: lane l31 -> q-row, k = 16*tk + 8*hi32 + e
  int qbase = qt * 128 + w * 32;
  const u16* Qp = Q + ((size_t)bh * NSEQ + qbase + l31) * HDIM;
  bf16x8 qf[4];
#pragma unroll
  for (int tk = 0; tk < 4; ++tk)
    qf[tk] = *(const bf16x8*)(Qp + 16 * tk + 8 * hi32);

  // prologue: stage chunks 0 and 1 (8 VMEM instr/thread each)
  stage16k<128>(Kb, HDIM, &bufK[0][0]);
  stage16k<256>(Vb, NSEQ, &bufV[0][0]);
  stage16k<128>(Kb + 128 * HDIM, HDIM, &bufK[1][0]);
  stage16k<256>(Vb + 128, NSEQ, &bufV[1][0]);

  f32x16 accO[2];
#pragma unroll
  for (int r = 0; r < 16; ++r) { accO[0][r] = 0.f; accO[1][r] = 0.f; }
  float m_run = -1e30f, den = 0.f;
  const float inv32 = 0.03125f;      // 1/sqrt(EMB)

  for (int c = 0; c < 4; ++c) {
    if (c == 3) asm volatile("s_waitcnt vmcnt(0)" ::: "memory");
    else        asm volatile("s_waitcnt vmcnt(8)" ::: "memory");   // own chunk landed
    asm volatile("s_barrier" ::: "memory");
    // ---- S chunk: 4 key-tiles x 4 k-steps of mfma32(K, Q) ----
    const char* smK = (const char*)&bufK[c & 1][0];
    f32x16 s[4];
    __builtin_amdgcn_s_setprio(1);
#pragma unroll
    for (int kt = 0; kt < 4; ++kt) {
#pragma unroll
      for (int r = 0; r < 16; ++r) s[kt][r] = 0.f;
#pragma unroll
      for (int tk = 0; tk < 4; ++tk) {
        int row = kt * 32 + l31;
        bf16x8 kf = *(const bf16x8*)(smK + row * 128 +
                      ((32 * tk + 16 * hi32) ^ ((row & 7) << 4)));
        s[kt] = __builtin_amdgcn_mfma_f32_32x32x16_bf16(kf, qf[tk], s[kt], 0, 0, 0);
      }
    }
    __builtin_amdgcn_s_setprio(0);
    // ---- online softmax (row = in-lane + xor32 partner) ----
    float mc = -1e30f;
#pragma unroll
    for (int kt = 0; kt < 4; ++kt)
#pragma unroll
      for (int r = 0; r < 16; ++r) mc = fmaxf(mc, s[kt][r]);
    mc = fmaxf(mc, __shfl_xor(mc, 32));
    float newm = fmaxf(m_run, mc);
    float fac = __expf((m_run - newm) * inv32);
    den *= fac;
#pragma unroll
    for (int r = 0; r < 16; ++r) { accO[0][r] *= fac; accO[1][r] *= fac; }
    m_run = newm;
#pragma unroll
    for (int kt = 0; kt < 4; ++kt)
#pragma unroll
      for (int r = 0; r < 16; ++r) {
        float p = __expf((s[kt][r] - newm) * inv32);
        den += p;
        s[kt][r] = p;
      }
    // pack P to bf16 pairs: pb[j] = {p[2j] lo, p[2j+1] hi}
    uint32_t pb[32];
#pragma unroll
    for (int j = 0; j < 32; ++j) {
      float lo = s[j >> 3][(2 * j) & 15];
      float hi = s[j >> 3][((2 * j) & 15) + 1];
      asm("v_cvt_pk_bf16_f32 %0, %1, %2" : "=v"(pb[j]) : "v"(lo), "v"(hi));
    }
    // ---- PV: per k-step build A-frag via 2 permlane32_swap ----
    const char* smV = (const char*)&bufV[c & 1][0];
#pragma unroll
    for (int ks = 0; ks < 8; ++ks) {
      uint32_t x0 = pb[4 * ks], y0 = pb[4 * ks + 2];
      uint32_t x1 = pb[4 * ks + 1], y1 = pb[4 * ks + 3];
      asm("v_permlane32_swap_b32 %0, %1" : "+v"(x0), "+v"(y0));
      asm("v_permlane32_swap_b32 %0, %1" : "+v"(x1), "+v"(y1));
      union { uint4 u; bf16x8 v; } pa;
      pa.u = make_uint4(x0, x1, y0, y1);
      __builtin_amdgcn_s_setprio(1);
#pragma unroll
      for (int dt = 0; dt < 2; ++dt) {
        int row = dt * 32 + l31;
        bf16x8 vb = *(const bf16x8*)(smV + row * 256 +
                      ((32 * ks + 16 * hi32) ^ ((row & 7) << 4)));
        accO[dt] = __builtin_amdgcn_mfma_f32_32x32x16_bf16(pa.v, vb, accO[dt], 0, 0, 0);
      }
      __builtin_amdgcn_s_setprio(0);
    }
    asm volatile("s_barrier" ::: "memory");   // all waves released buf[c&1]
    if (c + 2 < 4) {
      stage16k<128>(Kb + (size_t)(c + 2) * 128 * HDIM, HDIM, &bufK[c & 1][0]);
      stage16k<256>(Vb + (c + 2) * 128, NSEQ, &bufV[c & 1][0]);
    }
  }

  // ---- epilogue: O[q][d], q=(r&3)+8*(r>>2)+4*hi32, d=l31+32*dt ----
  float denf = den + __shfl_xor(den, 32);
  float rden = 1.0f / denf;
  int b_ = bh >> 4, hh = bh & 15;
#pragma unroll
  for (int r = 0; r < 16; ++r) {
    int qoff = (r & 3) + 8 * (r >> 2) + 4 * hi32;
    float rd = __shfl(rden, qoff);
    int tok = qbase + qoff;
    size_t base = ((size_t)(b_ * NSEQ + tok)) * EMB + hh * 64 + l31;
    AO[base]      = f2bf(accO[0][r] * rd);
    AO[base + 32] = f2bf(accO[1][r] * rd);
  }
}

// ---------------- launch ---------------------------------------------------
extern "C" void kernel_launch(void* const* d_in, const int* in_sizes, int n_in,
                              void* d_out, int out_size, void* d_ws, size_t ws_size,
                              hipStream_t stream)
{
  const float* x    = (const float*)d_in[0];
  const float* cls  = (const float*)d_in[1];
  const float* pos  = (const float*)d_in[2];
  const float* Wq   = (const float*)d_in[3];
  const float* Wk   = (const float*)d_in[4];
  const float* Wv   = (const float*)d_in[5];
  const float* Wp   = (const float*)d_in[6];
  const float* ln1g = (const float*)d_in[7];
  const float* ln1b = (const float*)d_in[8];
  const float* ln2g = (const float*)d_in[9];
  const float* ln2b = (const float*)d_in[10];
  const float* W1   = (const float*)d_in[11];
  const float* b1   = (const float*)d_in[12];
  const float* W2   = (const float*)d_in[13];
  const float* b2   = (const float*)d_in[14];
  float* H = (float*)d_out;          // residual stream lives in d_out (fp32)

  char* ws = (char*)d_ws;            // 160 MiB used
  u16* wqkv = (u16*)(ws + 0);                // [6][3072][1024] bf16 (B^T)
  u16* wp   = (u16*)(ws + 37748736);         // [6][1024][1024]
  u16* w1t  = (u16*)(ws + 50331648);         // [6][2048][1024]
  u16* w2t  = (u16*)(ws + 75497472);         // [6][1024][2048]
  u16* xn   = (u16*)(ws + 100663296);        // [8192][1024] (also attn out)
  u16* qb   = (u16*)(ws + 117440512);        // [256][512][64]
  u16* kb   = (u16*)(ws + 134217728);        // [256][512][64]
  u16* vtb  = (u16*)(ws + 150994944);        // [256][64][512]
  u16* ffb  = qb;                            // [8192][2048] aliases q+k

  wprep_all<<<6144, 256, 0, stream>>>(Wq, Wk, Wv, Wp, W1, W2,
                                      wqkv, wp, w1t, w2t);
  embed_k<<<NTOK, 256, 0, stream>>>(x, cls, pos, H);

  for (int l = 0; l < DEPTH; ++l) {
    ln_k<<<2048, 256, 0, stream>>>(H, ln1g + l * EMB, ln1b + l * EMB, xn);
    gemm_k<0><<<64 * 24, 256, 0, stream>>>(xn, wqkv + (size_t)l * 3145728, 24, 1024,
                                           nullptr, nullptr, nullptr, qb, kb, vtb);
    attn_k<<<1024, 256, 0, stream>>>(qb, kb, vtb, xn);
    gemm_k<1><<<64 * 8, 256, 0, stream>>>(xn, wp + (size_t)l * 1048576, 8, 1024,
                                          nullptr, H, nullptr, nullptr, nullptr, nullptr);
    ln_k<<<2048, 256, 0, stream>>>(H, ln2g + l * EMB, ln2b + l * EMB, xn);
    gemm_k<2><<<64 * 16, 256, 0, stream>>>(xn, w1t + (size_t)l * 2097152, 16, 1024,
                                           b1 + l * FFD, nullptr, ffb, nullptr, nullptr, nullptr);
    gemm_k<3><<<64 * 8, 256, 0, stream>>>(ffb, w2t + (size_t)l * 2097152, 8, 2048,
                                          b2 + l * EMB, H, nullptr, nullptr, nullptr, nullptr);
  }
}